// Round 6
// baseline (354.248 us; speedup 1.0000x reference)
//
#include <hip/hip_runtime.h>
#include <hip/hip_bf16.h>
#include <math.h>
#include <stdint.h>

#define VV 20000
#define LL 128
#define DD 256
#define DEMO_ 70
#define HID_ 1024
#define NN 2048

typedef __attribute__((ext_vector_type(8))) short short8;
typedef __attribute__((ext_vector_type(4))) float f32x4;

// ---- bf16 helpers ----
__device__ __forceinline__ float bf2f(uint32_t u) {
    union { uint32_t u; float f; } c; c.u = u << 16; return c.f;
}
__device__ __forceinline__ uint32_t f2bf(float f) {
    union { float f; uint32_t u; } c; c.f = f;
    return (c.u + 0x7fffu + ((c.u >> 16) & 1u)) >> 16;   // RNE
}

// swizzled halfword offset inside a [128][256] bf16 LDS tile
__device__ __forceinline__ int sw_off(int row, int col) {
    return (row << 8) + ((((col >> 3) ^ (row & 7)) << 3) | (col & 7));
}

// ---- fused pre-kernel ----
// blocks 0..255   : Mx = Wq @ Wk^T -> frag-major bf16
// blocks 256..319 : W1eff fold (k>=70): 8-k-tile x 512-h, FMA-dense
// blocks 320..351 : W1eff copy (k<70) + zero padding (k>=326)
// block 352       : LPT order ; block 353: init z/out
__global__ __launch_bounds__(256) void k_pre(
    const float* __restrict__ Wq, const float* __restrict__ Wk,
    const float* __restrict__ Wv, const float* __restrict__ W1,
    const float* __restrict__ ca, const float* __restrict__ cp,
    const int* __restrict__ lens,
    unsigned short* __restrict__ Mxf, unsigned short* __restrict__ W1f,
    int* __restrict__ order, float* __restrict__ z, float* __restrict__ out)
{
    __shared__ float sm[DD];
    __shared__ float wvs[8][DD];
    __shared__ int cnt[9], off[9], cur[9];
    const int b = blockIdx.x, t = threadIdx.x;

    if (b < 256) {
        int e = b;
        sm[t] = Wq[(size_t)e * DD + t];
        __syncthreads();
        const float4* wk4 = (const float4*)(Wk + (size_t)t * DD);
        const float4* wq4 = (const float4*)sm;
        float4 acc = make_float4(0.f, 0.f, 0.f, 0.f);
        for (int c = 0; c < DD / 4; ++c) {
            float4 a = wq4[c]; float4 bb = wk4[c];
            acc.x += a.x * bb.x; acc.y += a.y * bb.y;
            acc.z += a.z * bb.z; acc.w += a.w * bb.w;
        }
        float val = acc.x + acc.y + acc.z + acc.w;
        int frag = (e >> 4) * 8 + (t >> 5);
        int pos  = (((t >> 3) & 3) * 16 + (e & 15)) * 8 + (t & 7);
        Mxf[(size_t)frag * 512 + pos] = (unsigned short)f2bf(val);
    } else if (b < 320) {
        // fold: k = 70 + kg*8 + r (r=0..7), h = hh*512 + t (+256)
        int f = b - 256, kg = f >> 1, hh = f & 1;
        #pragma unroll
        for (int r = 0; r < 8; ++r)
            wvs[r][t] = Wv[(size_t)(kg * 8 + r) * DD + t];
        __syncthreads();
        int h0 = hh * 512 + t;
        float acc[8][2];
        #pragma unroll
        for (int r = 0; r < 8; ++r) { acc[r][0] = 0.f; acc[r][1] = 0.f; }
        #pragma unroll 2
        for (int n = 0; n < DD; ++n) {
            float a = W1[(size_t)(DEMO_ + n) * HID_ + h0];
            float c = W1[(size_t)(DEMO_ + n) * HID_ + h0 + 256];
            #pragma unroll
            for (int r = 0; r < 8; ++r) {
                float w = wvs[r][n];
                acc[r][0] += w * a; acc[r][1] += w * c;
            }
        }
        #pragma unroll
        for (int r = 0; r < 8; ++r)
            #pragma unroll
            for (int e2 = 0; e2 < 2; ++e2) {
                int k = DEMO_ + kg * 8 + r;
                int h = h0 + e2 * 256;
                int frag = (h >> 4) * 11 + (k >> 5);
                int pos  = (((k >> 3) & 3) * 16 + (h & 15)) * 8 + (k & 7);
                W1f[(size_t)frag * 512 + pos] = (unsigned short)f2bf(acc[r][e2]);
            }
    } else if (b < 352) {
        // copy k<70 rows + zero pads k=326..351  (96*1024 elements)
        int g = b - 320;
        for (int idx = g * 256 + t; idx < 96 * 1024; idx += 32 * 256) {
            int kk = idx >> 10, h = idx & 1023;
            int k = kk < DEMO_ ? kk : kk + 256;
            float val = kk < DEMO_ ? W1[(size_t)kk * HID_ + h] : 0.f;
            int frag = (h >> 4) * 11 + (k >> 5);
            int pos  = (((k >> 3) & 3) * 16 + (h & 15)) * 8 + (k & 7);
            W1f[(size_t)frag * 512 + pos] = (unsigned short)f2bf(val);
        }
    } else if (b == 352) {
        if (t < 9) cnt[t] = 0;
        __syncthreads();
        for (int i = t; i < NN; i += 256)
            atomicAdd(&cnt[(lens[i] + 15) >> 4], 1);
        __syncthreads();
        if (t == 0) {
            int acc = 0;
            for (int k = 8; k >= 1; --k) { off[k] = acc; acc += cnt[k]; cur[k] = off[k]; }
        }
        __syncthreads();
        for (int i = t; i < NN; i += 256) {
            int key = (lens[i] + 15) >> 4;
            int pos = atomicAdd(&cur[key], 1);
            order[pos] = i;
        }
    } else {
        for (int i = t; i < NN; i += 256) z[i] = 0.f;
        if (t == 0) out[0] = ca[0] * ca[0] + cp[0] * cp[0];
    }
}

// ---- kernel 2: persistent per-sample attention+pooling. 512 blocks x 512 thr ----
__global__ __launch_bounds__(512, 4) __attribute__((amdgpu_waves_per_eu(4, 4)))
void k_main(
    const float* __restrict__ E,
    const float* __restrict__ ht,  const float* __restrict__ evt_t,
    const int* __restrict__ codes, const int* __restrict__ lens,
    const float* __restrict__ ca_p, const float* __restrict__ cp_p,
    const unsigned short* __restrict__ Mxf,
    const int* __restrict__ order,
    unsigned short* __restrict__ Rbf)
{
    __shared__ __align__(16) unsigned short emb_u[LL * DD];   // 64 KB; H in place
    __shared__ float times_s[LL];
    __shared__ int   codes_s[LL];
    __shared__ float w_s[LL];
    __shared__ float apart[8][LL];
    __shared__ float rp_part[8][DD];
    __shared__ float asum[LL];

    const int tid = threadIdx.x, wv = tid >> 6, ln = tid & 63;
    const int q = ln >> 4, m = ln & 15;
    const float ca = ca_p[0], cp = cp_p[0];

    // ---- bB: loaded ONCE per block, lives in VGPRs for all 4 samples
    short8 bB[2][8];
    #pragma unroll
    for (int nt = 0; nt < 2; ++nt)
        #pragma unroll
        for (int kk = 0; kk < 8; ++kk)
            bB[nt][kk] = *(const short8*)(Mxf + (size_t)((wv * 2 + nt) * 8 + kk) * 512 + ln * 8);

    for (int rep = 0; rep < 4; ++rep) {
        const int n = order[blockIdx.x + 512 * rep];
        const int len = lens[n];
        const int it_n = (len + 15) >> 4;
        const float evt = evt_t[n];

        // ---- stage times/codes + pooling weights
        if (tid < LL) {
            bool v = tid < len;
            times_s[tid] = v ? ht[(size_t)n * LL + tid] : 0.f;
            codes_s[tid] = v ? codes[(size_t)n * LL + tid] : 0;
        }
        if (wv == 0) {
            float t0 = (ln      < len) ? ht[(size_t)n * LL + ln]      : 0.f;
            float t1 = (ln + 64 < len) ? ht[(size_t)n * LL + ln + 64] : 0.f;
            float e0 = (ln      < len) ? __expf(cp * (t0 - evt)) : 0.f;
            float e1 = (ln + 64 < len) ? __expf(cp * (t1 - evt)) : 0.f;
            float smm = e0 + e1;
            for (int o = 32; o; o >>= 1) smm += __shfl_xor(smm, o, 64);
            float inv = 1.f / smm;
            if (ln      < len) w_s[ln]      = e0 * inv;
            if (ln + 64 < len) w_s[ln + 64] = e1 * inv;
        }
        __syncthreads();

        // ---- gather E rows -> swizzled bf16 LDS, 4 rows in flight per wave
        for (int l0 = wv; l0 < len; l0 += 32) {
            float4 v[4];
            #pragma unroll
            for (int u = 0; u < 4; ++u) {
                int l = l0 + u * 8;
                if (l < len)
                    v[u] = ((const float4*)(E + (size_t)codes_s[l] * DD))[ln];
            }
            #pragma unroll
            for (int u = 0; u < 4; ++u) {
                int l = l0 + u * 8;
                if (l < len)
                    *(uint2*)&emb_u[sw_off(l, 4 * ln)] =
                        make_uint2(f2bf(v[u].x) | (f2bf(v[u].y) << 16),
                                   f2bf(v[u].z) | (f2bf(v[u].w) << 16));
            }
        }
        __syncthreads();

        // ---- phase B: H = emb @ Mx^T, in place tile-by-tile
        short8 aC[8];
        for (int it = 0; it < it_n; ++it) {
            f32x4 h0 = (f32x4)0.f, h1 = (f32x4)0.f;
            #pragma unroll
            for (int kk = 0; kk < 8; ++kk) {
                short8 af = *(const short8*)&emb_u[sw_off(it * 16 + m, kk * 32 + q * 8)];
                if (it == wv) aC[kk] = af;   // wave-uniform
                h0 = __builtin_amdgcn_mfma_f32_16x16x32_bf16(af, bB[0][kk], h0, 0, 0, 0);
                h1 = __builtin_amdgcn_mfma_f32_16x16x32_bf16(af, bB[1][kk], h1, 0, 0, 0);
            }
            __syncthreads();
            #pragma unroll
            for (int r = 0; r < 4; ++r) {
                int row = it * 16 + q * 4 + r;
                emb_u[sw_off(row, wv * 32 + m)]      = (unsigned short)f2bf(h0[r]);
                emb_u[sw_off(row, wv * 32 + 16 + m)] = (unsigned short)f2bf(h1[r]);
            }
        }
        __syncthreads();

        // ---- phase C: wave wv owns row tile it=wv; S in registers
        if (wv < it_n) {
            f32x4 sac[8];
            #pragma unroll
            for (int jt = 0; jt < 8; ++jt) sac[jt] = (f32x4)0.f;
            for (int jt = 0; jt < it_n; ++jt) {
                #pragma unroll
                for (int kk = 0; kk < 8; ++kk) {
                    short8 bH = *(const short8*)&emb_u[sw_off(jt * 16 + m, kk * 32 + q * 8)];
                    sac[jt] = __builtin_amdgcn_mfma_f32_16x16x32_bf16(aC[kk], bH, sac[jt], 0, 0, 0);
                }
            }
            int i_base = wv * 16 + q * 4;
            float ti[4]; bool vR[4]; float rowsum[4];
            #pragma unroll
            for (int r = 0; r < 4; ++r) {
                vR[r] = (i_base + r) < len;
                ti[r] = times_s[i_base + r];
                rowsum[r] = 0.f;
            }
            for (int jt = 0; jt < it_n; ++jt) {
                int jcol = jt * 16 + m;
                bool vC = jcol < len;
                float tj = times_s[jcol];
                #pragma unroll
                for (int r = 0; r < 4; ++r) {
                    float arg = sac[jt][r] * 0.0625f - ca * fabsf(ti[r] - tj);
                    float p = (vR[r] && vC) ? __expf(arg) : 0.f;
                    sac[jt][r] = p;
                    rowsum[r] += p;
                }
            }
            #pragma unroll
            for (int r = 0; r < 4; ++r) {
                float s = rowsum[r];
                s += __shfl_xor(s, 1, 64); s += __shfl_xor(s, 2, 64);
                s += __shfl_xor(s, 4, 64); s += __shfl_xor(s, 8, 64);
                rowsum[r] = s;
            }
            float sc[4];
            #pragma unroll
            for (int r = 0; r < 4; ++r)
                sc[r] = (vR[r] && rowsum[r] > 0.f) ? w_s[i_base + r] / rowsum[r] : 0.f;
            for (int jt = 0; jt < it_n; ++jt) {
                float v = sc[0] * sac[jt][0] + sc[1] * sac[jt][1]
                        + sc[2] * sac[jt][2] + sc[3] * sac[jt][3];
                v += __shfl_xor(v, 16, 64);
                v += __shfl_xor(v, 32, 64);
                if (q == 0) apart[wv][jt * 16 + m] = v;
            }
        }
        __syncthreads();

        if (tid < LL) {
            float s = 0.f;
            for (int r = 0; r < it_n; ++r) s += apart[r][tid];
            asum[tid] = s;
        }
        __syncthreads();

        // ---- phase D: rp[e] = sum_j a_j * emb[j][e], from aC registers
        if (wv < it_n) {
            float aw = asum[wv * 16 + m];
            #pragma unroll
            for (int kk = 0; kk < 8; ++kk) {
                float v[8];
                #pragma unroll
                for (int j = 0; j < 8; ++j)
                    v[j] = aw * bf2f((uint32_t)(unsigned short)aC[kk][j]);
                #pragma unroll
                for (int o = 1; o <= 8; o <<= 1)
                    #pragma unroll
                    for (int j = 0; j < 8; ++j)
                        v[j] += __shfl_xor(v[j], o, 64);
                if (m < 8)
                    rp_part[wv][kk * 32 + q * 8 + m] = v[m];
            }
        }
        __syncthreads();
        if (tid < DD) {
            float r = 0.f;
            for (int t2 = 0; t2 < it_n; ++t2) r += rp_part[t2][tid];
            Rbf[(size_t)n * DD + tid] = (unsigned short)f2bf(r);
        }
        __syncthreads();
    }
}

// ---- kernel 3: batched MLP partial-z. 32 samples/block, grid (NN/32, 4) ----
__global__ __launch_bounds__(256) void k_mlp(
    const float* __restrict__ demo,
    const float* __restrict__ b1,   const float* __restrict__ W2,
    const unsigned short* __restrict__ Rbf,
    const unsigned short* __restrict__ W1f,
    float* __restrict__ z)
{
    __shared__ __align__(16) unsigned short xs[32][360];
    __shared__ float W2s[256];
    __shared__ float b1s[256];
    __shared__ float wred[4][32];

    const int tid = threadIdx.x, wv = tid >> 6, ln = tid & 63;
    const int q = ln >> 4, m = ln & 15;
    const int s0 = blockIdx.x * 32;
    const int by = blockIdx.y;
    const int hbase = by * 256;

    W2s[tid] = W2[hbase + tid];
    b1s[tid] = b1[hbase + tid];
    for (int s = 0; s < 32; ++s) {
        if (tid < DEMO_) xs[s][tid] = (unsigned short)f2bf(demo[(size_t)(s0 + s) * DEMO_ + tid]);
        xs[s][DEMO_ + tid] = Rbf[(size_t)(s0 + s) * DD + tid];
        if (tid < 34) xs[s][326 + tid] = 0;
    }
    __syncthreads();

    f32x4 cacc[2][4];
    #pragma unroll
    for (int mt = 0; mt < 2; ++mt)
        #pragma unroll
        for (int ntl = 0; ntl < 4; ++ntl) cacc[mt][ntl] = (f32x4)0.f;

    for (int kk = 0; kk < 11; ++kk) {
        short8 af0 = *(const short8*)&xs[m][kk * 32 + q * 8];
        short8 af1 = *(const short8*)&xs[16 + m][kk * 32 + q * 8];
        #pragma unroll
        for (int ntl = 0; ntl < 4; ++ntl) {
            int frag = (by * 16 + wv * 4 + ntl) * 11 + kk;
            short8 bfd = *(const short8*)(W1f + (size_t)frag * 512 + ln * 8);
            cacc[0][ntl] = __builtin_amdgcn_mfma_f32_16x16x32_bf16(af0, bfd, cacc[0][ntl], 0, 0, 0);
            cacc[1][ntl] = __builtin_amdgcn_mfma_f32_16x16x32_bf16(af1, bfd, cacc[1][ntl], 0, 0, 0);
        }
    }

    #pragma unroll
    for (int mt = 0; mt < 2; ++mt) {
        float ls0 = 0.f, ls1 = 0.f, ls2 = 0.f, ls3 = 0.f;
        #pragma unroll
        for (int ntl = 0; ntl < 4; ++ntl) {
            int hl = wv * 64 + ntl * 16 + m;
            float bb = b1s[hl], w2v = W2s[hl];
            ls0 += fmaxf(cacc[mt][ntl][0] + bb, 0.f) * w2v;
            ls1 += fmaxf(cacc[mt][ntl][1] + bb, 0.f) * w2v;
            ls2 += fmaxf(cacc[mt][ntl][2] + bb, 0.f) * w2v;
            ls3 += fmaxf(cacc[mt][ntl][3] + bb, 0.f) * w2v;
        }
        #pragma unroll
        for (int o = 1; o <= 8; o <<= 1) {
            ls0 += __shfl_xor(ls0, o, 64); ls1 += __shfl_xor(ls1, o, 64);
            ls2 += __shfl_xor(ls2, o, 64); ls3 += __shfl_xor(ls3, o, 64);
        }
        if (m == 0) {
            wred[wv][mt * 16 + q * 4 + 0] = ls0; wred[wv][mt * 16 + q * 4 + 1] = ls1;
            wred[wv][mt * 16 + q * 4 + 2] = ls2; wred[wv][mt * 16 + q * 4 + 3] = ls3;
        }
    }
    __syncthreads();
    if (tid < 32)
        atomicAdd(&z[s0 + tid], wred[0][tid] + wred[1][tid] + wred[2][tid] + wred[3][tid]);
}

// ---- kernel 4: BCE loss over z ----
__global__ __launch_bounds__(256) void k_loss(const float* __restrict__ labels,
                                              const float* __restrict__ b2,
                                              const float* __restrict__ z,
                                              float* __restrict__ out) {
    __shared__ float red[4];
    int tid = threadIdx.x, wv = tid >> 6;
    int i = blockIdx.x * 256 + tid;
    float zz = z[i] + b2[0];
    float y = labels[i];
    float lg = log1pf(__expf(-fabsf(zz)));
    float loss = 2.f * y * (fmaxf(-zz, 0.f) + lg) + (1.f - y) * (fmaxf(zz, 0.f) + lg);
    for (int o = 32; o; o >>= 1) loss += __shfl_xor(loss, o, 64);
    if ((tid & 63) == 0) red[wv] = loss;
    __syncthreads();
    if (tid == 0)
        atomicAdd(out, (red[0] + red[1] + red[2] + red[3]) * (1.f / (float)NN));
}

extern "C" void kernel_launch(void* const* d_in, const int* in_sizes, int n_in,
                              void* d_out, int out_size, void* d_ws, size_t ws_size,
                              hipStream_t stream) {
    const float* E      = (const float*)d_in[0];
    const float* Wq     = (const float*)d_in[1];
    const float* Wk     = (const float*)d_in[2];
    const float* Wv     = (const float*)d_in[3];
    const float* ca     = (const float*)d_in[4];
    const float* cp     = (const float*)d_in[5];
    const float* W1     = (const float*)d_in[6];
    const float* b1     = (const float*)d_in[7];
    const float* W2     = (const float*)d_in[8];
    const float* b2     = (const float*)d_in[9];
    const float* demo   = (const float*)d_in[10];
    const float* ht     = (const float*)d_in[11];
    const float* evt    = (const float*)d_in[12];
    const float* labels = (const float*)d_in[13];
    const int*   codes  = (const int*)d_in[14];
    const int*   lens   = (const int*)d_in[15];
    float* out = (float*)d_out;

    unsigned short* Mxf = (unsigned short*)d_ws;                           // 128 KB
    unsigned short* W1f = (unsigned short*)((char*)d_ws + 131072);         // 704 KB
    unsigned short* Rbf = (unsigned short*)((char*)d_ws + 851968);         // 1 MB
    float*          zar = (float*)((char*)d_ws + 1900544);                 // 8 KB
    int*            ord = (int*)((char*)d_ws + 1908736);                   // 8 KB

    hipLaunchKernelGGL(k_pre,  dim3(354), dim3(256), 0, stream,
                       Wq, Wk, Wv, W1, ca, cp, lens, Mxf, W1f, ord, zar, out);
    hipLaunchKernelGGL(k_main, dim3(512), dim3(512), 0, stream,
                       E, ht, evt, codes, lens, ca, cp, Mxf, ord, Rbf);
    hipLaunchKernelGGL(k_mlp,  dim3(NN / 32, 4), dim3(256), 0, stream,
                       demo, b1, W2, Rbf, W1f, zar);
    hipLaunchKernelGGL(k_loss, dim3(NN / 256), dim3(256), 0, stream, labels, b2, zar, out);
}

// Round 7
// 251.501 us; speedup vs baseline: 1.4085x; 1.4085x over previous
//
#include <hip/hip_runtime.h>
#include <hip/hip_bf16.h>
#include <math.h>
#include <stdint.h>

#define VV 20000
#define LL 128
#define DD 256
#define DEMO_ 70
#define HID_ 1024
#define NN 2048

typedef __attribute__((ext_vector_type(8))) short short8;
typedef __attribute__((ext_vector_type(4))) float f32x4;

// ---- bf16 helpers ----
__device__ __forceinline__ float bf2f(uint32_t u) {
    union { uint32_t u; float f; } c; c.u = u << 16; return c.f;
}
__device__ __forceinline__ uint32_t f2bf(float f) {
    union { float f; uint32_t u; } c; c.f = f;
    return (c.u + 0x7fffu + ((c.u >> 16) & 1u)) >> 16;   // RNE
}

// swizzled halfword offset inside a [128][256] bf16 LDS tile
__device__ __forceinline__ int sw_off(int row, int col) {
    return (row << 8) + ((((col >> 3) ^ (row & 7)) << 3) | (col & 7));
}

// ---- fused pre-kernel ----
// blocks 0..255   : Mx = Wq @ Wk^T -> frag-major bf16
// blocks 256..383 : W1eff fold (k>=70): 8-k x 256-h per block, 8x reuse
// blocks 384..415 : W1eff copy (k<70) + zero padding (k>=326)
// block 416       : LPT order + out init
__global__ __launch_bounds__(256) void k_pre(
    const float* __restrict__ Wq, const float* __restrict__ Wk,
    const float* __restrict__ Wv, const float* __restrict__ W1,
    const float* __restrict__ ca, const float* __restrict__ cp,
    const int* __restrict__ lens,
    unsigned short* __restrict__ Mxf, unsigned short* __restrict__ W1f,
    int* __restrict__ order, float* __restrict__ out)
{
    __shared__ float sm[DD];
    __shared__ float wvs[8][DD];
    __shared__ int cnt[9], off[9], cur[9];
    const int b = blockIdx.x, t = threadIdx.x;

    if (b < 256) {
        int e = b;
        sm[t] = Wq[(size_t)e * DD + t];
        __syncthreads();
        const float4* wk4 = (const float4*)(Wk + (size_t)t * DD);
        const float4* wq4 = (const float4*)sm;
        float4 acc = make_float4(0.f, 0.f, 0.f, 0.f);
        #pragma unroll 8
        for (int c = 0; c < DD / 4; ++c) {
            float4 a = wq4[c]; float4 bb = wk4[c];
            acc.x += a.x * bb.x; acc.y += a.y * bb.y;
            acc.z += a.z * bb.z; acc.w += a.w * bb.w;
        }
        float val = acc.x + acc.y + acc.z + acc.w;
        int frag = (e >> 4) * 8 + (t >> 5);
        int pos  = (((t >> 3) & 3) * 16 + (e & 15)) * 8 + (t & 7);
        Mxf[(size_t)frag * 512 + pos] = (unsigned short)f2bf(val);
    } else if (b < 384) {
        // fold: k = 70 + kg*8 + r, h = hh*256 + t
        int f = b - 256, kg = f >> 2, hh = f & 3;
        #pragma unroll
        for (int r = 0; r < 8; ++r)
            wvs[r][t] = Wv[(size_t)(kg * 8 + r) * DD + t];
        __syncthreads();
        int h = hh * 256 + t;
        float acc[8];
        #pragma unroll
        for (int r = 0; r < 8; ++r) acc[r] = 0.f;
        #pragma unroll 4
        for (int n = 0; n < DD; ++n) {
            float a = W1[(size_t)(DEMO_ + n) * HID_ + h];
            #pragma unroll
            for (int r = 0; r < 8; ++r) acc[r] += wvs[r][n] * a;
        }
        #pragma unroll
        for (int r = 0; r < 8; ++r) {
            int k = DEMO_ + kg * 8 + r;
            int frag = (h >> 4) * 11 + (k >> 5);
            int pos  = (((k >> 3) & 3) * 16 + (h & 15)) * 8 + (k & 7);
            W1f[(size_t)frag * 512 + pos] = (unsigned short)f2bf(acc[r]);
        }
    } else if (b < 416) {
        // copy k<70 rows + zero pads k=326..351  (96*1024 elements)
        int g = b - 384;
        for (int idx = g * 256 + t; idx < 96 * 1024; idx += 32 * 256) {
            int kk = idx >> 10, h = idx & 1023;
            int k = kk < DEMO_ ? kk : kk + 256;
            float val = kk < DEMO_ ? W1[(size_t)kk * HID_ + h] : 0.f;
            int frag = (h >> 4) * 11 + (k >> 5);
            int pos  = (((k >> 3) & 3) * 16 + (h & 15)) * 8 + (k & 7);
            W1f[(size_t)frag * 512 + pos] = (unsigned short)f2bf(val);
        }
    } else {
        if (t < 9) cnt[t] = 0;
        __syncthreads();
        for (int i = t; i < NN; i += 256)
            atomicAdd(&cnt[(lens[i] + 15) >> 4], 1);
        __syncthreads();
        if (t == 0) {
            int acc = 0;
            for (int k = 8; k >= 1; --k) { off[k] = acc; acc += cnt[k]; cur[k] = off[k]; }
            out[0] = ca[0] * ca[0] + cp[0] * cp[0];
        }
        __syncthreads();
        for (int i = t; i < NN; i += 256) {
            int key = (lens[i] + 15) >> 4;
            int pos = atomicAdd(&cur[key], 1);
            order[pos] = i;
        }
    }
}

// ---- kernel 2: per-sample attention+pooling -> rp (bf16). 512 thr, 2 blocks/CU ----
__global__ __launch_bounds__(512, 4) void k_main(
    const float* __restrict__ E,
    const float* __restrict__ ht,  const float* __restrict__ evt_t,
    const int* __restrict__ codes, const int* __restrict__ lens,
    const float* __restrict__ ca_p, const float* __restrict__ cp_p,
    const unsigned short* __restrict__ Mxf,
    const int* __restrict__ order,
    unsigned short* __restrict__ Rbf)
{
    __shared__ __align__(16) unsigned short emb_u[LL * DD];   // 64 KB; H overwrites in place
    __shared__ float times_s[LL];
    __shared__ int   codes_s[LL];
    __shared__ float w_s[LL];
    __shared__ float apart[8][LL];      // 4 KB
    __shared__ float rp_part[8][DD];    // 8 KB
    __shared__ float asum[LL];

    const int n = order[blockIdx.x];
    const int tid = threadIdx.x, wv = tid >> 6, ln = tid & 63;
    const int q = ln >> 4, m = ln & 15;
    const int len = lens[n];
    const int it_n = (len + 15) >> 4;
    const float ca = ca_p[0], cp = cp_p[0];
    const float evt = evt_t[n];

    // ---- preload B-frags for phase B (in flight across gather)
    short8 bB[2][8];
    #pragma unroll
    for (int nt = 0; nt < 2; ++nt)
        #pragma unroll
        for (int kk = 0; kk < 8; ++kk)
            bB[nt][kk] = *(const short8*)(Mxf + (size_t)((wv * 2 + nt) * 8 + kk) * 512 + ln * 8);

    // ---- stage times/codes (waves 0-1); pooling weights from global (wave 0)
    if (tid < LL) {
        bool v = tid < len;
        times_s[tid] = v ? ht[(size_t)n * LL + tid] : 0.f;
        codes_s[tid] = v ? codes[(size_t)n * LL + tid] : 0;
    }
    if (wv == 0) {
        float t0 = (ln      < len) ? ht[(size_t)n * LL + ln]      : 0.f;
        float t1 = (ln + 64 < len) ? ht[(size_t)n * LL + ln + 64] : 0.f;
        float e0 = (ln      < len) ? __expf(cp * (t0 - evt)) : 0.f;
        float e1 = (ln + 64 < len) ? __expf(cp * (t1 - evt)) : 0.f;
        float smm = e0 + e1;
        for (int o = 32; o; o >>= 1) smm += __shfl_xor(smm, o, 64);
        float inv = 1.f / smm;
        if (ln      < len) w_s[ln]      = e0 * inv;
        if (ln + 64 < len) w_s[ln + 64] = e1 * inv;
    }
    __syncthreads();

    // ---- gather E rows -> swizzled bf16 LDS, 4 rows in flight per wave
    for (int l0 = wv; l0 < len; l0 += 32) {
        float4 v[4];
        #pragma unroll
        for (int u = 0; u < 4; ++u) {
            int l = l0 + u * 8;
            if (l < len)
                v[u] = ((const float4*)(E + (size_t)codes_s[l] * DD))[ln];
        }
        #pragma unroll
        for (int u = 0; u < 4; ++u) {
            int l = l0 + u * 8;
            if (l < len)
                *(uint2*)&emb_u[sw_off(l, 4 * ln)] =
                    make_uint2(f2bf(v[u].x) | (f2bf(v[u].y) << 16),
                               f2bf(v[u].z) | (f2bf(v[u].w) << 16));
        }
    }
    __syncthreads();

    // ---- phase B: H = emb @ Mx^T, overwriting emb tile-by-tile
    short8 aC[8];                        // cached A-frags for row tile wv
    for (int it = 0; it < it_n; ++it) {
        f32x4 h0 = (f32x4)0.f, h1 = (f32x4)0.f;
        #pragma unroll
        for (int kk = 0; kk < 8; ++kk) {
            short8 af = *(const short8*)&emb_u[sw_off(it * 16 + m, kk * 32 + q * 8)];
            if (it == wv) aC[kk] = af;   // wave-uniform
            h0 = __builtin_amdgcn_mfma_f32_16x16x32_bf16(af, bB[0][kk], h0, 0, 0, 0);
            h1 = __builtin_amdgcn_mfma_f32_16x16x32_bf16(af, bB[1][kk], h1, 0, 0, 0);
        }
        __syncthreads();                 // all waves done reading emb tile it
        #pragma unroll
        for (int r = 0; r < 4; ++r) {
            int row = it * 16 + q * 4 + r;
            emb_u[sw_off(row, wv * 32 + m)]      = (unsigned short)f2bf(h0[r]);
            emb_u[sw_off(row, wv * 32 + 16 + m)] = (unsigned short)f2bf(h1[r]);
        }
    }
    __syncthreads();                     // H fully materialized

    // ---- phase C: wave wv owns row tile it=wv; S in registers
    if (wv < it_n) {
        f32x4 sac[8];
        #pragma unroll
        for (int jt = 0; jt < 8; ++jt) sac[jt] = (f32x4)0.f;
        for (int jt = 0; jt < it_n; ++jt) {
            #pragma unroll
            for (int kk = 0; kk < 8; ++kk) {
                short8 bH = *(const short8*)&emb_u[sw_off(jt * 16 + m, kk * 32 + q * 8)];
                sac[jt] = __builtin_amdgcn_mfma_f32_16x16x32_bf16(aC[kk], bH, sac[jt], 0, 0, 0);
            }
        }
        int i_base = wv * 16 + q * 4;
        float ti[4]; bool vR[4]; float rowsum[4];
        #pragma unroll
        for (int r = 0; r < 4; ++r) {
            vR[r] = (i_base + r) < len;
            ti[r] = times_s[i_base + r];
            rowsum[r] = 0.f;
        }
        for (int jt = 0; jt < it_n; ++jt) {
            int jcol = jt * 16 + m;
            bool vC = jcol < len;
            float tj = times_s[jcol];
            #pragma unroll
            for (int r = 0; r < 4; ++r) {
                float arg = sac[jt][r] * 0.0625f - ca * fabsf(ti[r] - tj);
                float p = (vR[r] && vC) ? __expf(arg) : 0.f;
                sac[jt][r] = p;
                rowsum[r] += p;
            }
        }
        #pragma unroll
        for (int r = 0; r < 4; ++r) {
            float s = rowsum[r];
            s += __shfl_xor(s, 1, 64); s += __shfl_xor(s, 2, 64);
            s += __shfl_xor(s, 4, 64); s += __shfl_xor(s, 8, 64);
            rowsum[r] = s;
        }
        float sc[4];
        #pragma unroll
        for (int r = 0; r < 4; ++r)
            sc[r] = (vR[r] && rowsum[r] > 0.f) ? w_s[i_base + r] / rowsum[r] : 0.f;
        for (int jt = 0; jt < it_n; ++jt) {
            float v = sc[0] * sac[jt][0] + sc[1] * sac[jt][1]
                    + sc[2] * sac[jt][2] + sc[3] * sac[jt][3];
            v += __shfl_xor(v, 16, 64);
            v += __shfl_xor(v, 32, 64);
            if (q == 0) apart[wv][jt * 16 + m] = v;
        }
    }
    __syncthreads();

    if (tid < LL) {
        float s = 0.f;
        for (int r = 0; r < it_n; ++r) s += apart[r][tid];
        asum[tid] = s;
    }
    __syncthreads();

    // ---- phase D: rp[e] = sum_j a_j * emb[j][e], from aC registers
    if (wv < it_n) {
        float aw = asum[wv * 16 + m];
        #pragma unroll
        for (int kk = 0; kk < 8; ++kk) {
            float v[8];
            #pragma unroll
            for (int j = 0; j < 8; ++j)
                v[j] = aw * bf2f((uint32_t)(unsigned short)aC[kk][j]);
            #pragma unroll
            for (int o = 1; o <= 8; o <<= 1)
                #pragma unroll
                for (int j = 0; j < 8; ++j)
                    v[j] += __shfl_xor(v[j], o, 64);
            if (m < 8)
                rp_part[wv][kk * 32 + q * 8 + m] = v[m];
        }
    }
    __syncthreads();
    if (tid < DD) {
        float r = 0.f;
        for (int t2 = 0; t2 < it_n; ++t2) r += rp_part[t2][tid];
        Rbf[(size_t)n * DD + tid] = (unsigned short)f2bf(r);
    }
}

// ---- kernel 3: batched MLP + BCE. 16 samples x full 1024 hidden per block ----
__global__ __launch_bounds__(256, 2) void k_mlp(
    const float* __restrict__ demo, const float* __restrict__ labels,
    const float* __restrict__ b1,   const float* __restrict__ W2,
    const float* __restrict__ b2,
    const unsigned short* __restrict__ Rbf,
    const unsigned short* __restrict__ W1f,
    float* __restrict__ out)
{
    __shared__ __align__(16) unsigned short xs[16][360];
    __shared__ float W2s[HID_];
    __shared__ float b1s[HID_];
    __shared__ float wred[4][16];
    __shared__ float lred[16];

    const int tid = threadIdx.x, wv = tid >> 6, ln = tid & 63;
    const int q = ln >> 4, m = ln & 15;
    const int s0 = blockIdx.x * 16;

    #pragma unroll
    for (int hh = 0; hh < 4; ++hh) {
        W2s[tid + 256 * hh] = W2[tid + 256 * hh];
        b1s[tid + 256 * hh] = b1[tid + 256 * hh];
    }
    for (int s = 0; s < 16; ++s) {
        if (tid < DEMO_) xs[s][tid] = (unsigned short)f2bf(demo[(size_t)(s0 + s) * DEMO_ + tid]);
        xs[s][DEMO_ + tid] = Rbf[(size_t)(s0 + s) * DD + tid];
        if (tid < 34) xs[s][326 + tid] = 0;
    }
    __syncthreads();

    f32x4 cacc[16];
    #pragma unroll
    for (int ntl = 0; ntl < 16; ++ntl) cacc[ntl] = (f32x4)0.f;

    for (int kk = 0; kk < 11; ++kk) {
        short8 af = *(const short8*)&xs[m][kk * 32 + q * 8];
        #pragma unroll
        for (int ntl = 0; ntl < 16; ++ntl) {
            int frag = (wv * 16 + ntl) * 11 + kk;
            short8 bfd = *(const short8*)(W1f + (size_t)frag * 512 + ln * 8);
            cacc[ntl] = __builtin_amdgcn_mfma_f32_16x16x32_bf16(af, bfd, cacc[ntl], 0, 0, 0);
        }
    }

    float ls0 = 0.f, ls1 = 0.f, ls2 = 0.f, ls3 = 0.f;
    #pragma unroll
    for (int ntl = 0; ntl < 16; ++ntl) {
        int hl = wv * 256 + ntl * 16 + m;
        float bb = b1s[hl], w2v = W2s[hl];
        ls0 += fmaxf(cacc[ntl][0] + bb, 0.f) * w2v;
        ls1 += fmaxf(cacc[ntl][1] + bb, 0.f) * w2v;
        ls2 += fmaxf(cacc[ntl][2] + bb, 0.f) * w2v;
        ls3 += fmaxf(cacc[ntl][3] + bb, 0.f) * w2v;
    }
    #pragma unroll
    for (int o = 1; o <= 8; o <<= 1) {
        ls0 += __shfl_xor(ls0, o, 64); ls1 += __shfl_xor(ls1, o, 64);
        ls2 += __shfl_xor(ls2, o, 64); ls3 += __shfl_xor(ls3, o, 64);
    }
    if (m == 0) {
        wred[wv][q * 4 + 0] = ls0; wred[wv][q * 4 + 1] = ls1;
        wred[wv][q * 4 + 2] = ls2; wred[wv][q * 4 + 3] = ls3;
    }
    __syncthreads();
    if (tid < 16) {
        float z = wred[0][tid] + wred[1][tid] + wred[2][tid] + wred[3][tid] + b2[0];
        float y = labels[s0 + tid];
        float lg = log1pf(__expf(-fabsf(z)));
        float loss = 2.f * y * (fmaxf(-z, 0.f) + lg) + (1.f - y) * (fmaxf(z, 0.f) + lg);
        lred[tid] = loss;
    }
    __syncthreads();
    if (tid == 0) {
        float t = 0.f;
        #pragma unroll
        for (int i = 0; i < 16; ++i) t += lred[i];
        atomicAdd(out, t * (1.f / (float)NN));
    }
}

extern "C" void kernel_launch(void* const* d_in, const int* in_sizes, int n_in,
                              void* d_out, int out_size, void* d_ws, size_t ws_size,
                              hipStream_t stream) {
    const float* E      = (const float*)d_in[0];
    const float* Wq     = (const float*)d_in[1];
    const float* Wk     = (const float*)d_in[2];
    const float* Wv     = (const float*)d_in[3];
    const float* ca     = (const float*)d_in[4];
    const float* cp     = (const float*)d_in[5];
    const float* W1     = (const float*)d_in[6];
    const float* b1     = (const float*)d_in[7];
    const float* W2     = (const float*)d_in[8];
    const float* b2     = (const float*)d_in[9];
    const float* demo   = (const float*)d_in[10];
    const float* ht     = (const float*)d_in[11];
    const float* evt    = (const float*)d_in[12];
    const float* labels = (const float*)d_in[13];
    const int*   codes  = (const int*)d_in[14];
    const int*   lens   = (const int*)d_in[15];
    float* out = (float*)d_out;

    unsigned short* Mxf = (unsigned short*)d_ws;                           // 128 KB
    unsigned short* W1f = (unsigned short*)((char*)d_ws + 131072);         // 704 KB
    unsigned short* Rbf = (unsigned short*)((char*)d_ws + 851968);         // 1 MB
    int*            ord = (int*)((char*)d_ws + 1900544);                   // 8 KB

    hipLaunchKernelGGL(k_pre,  dim3(417), dim3(256), 0, stream,
                       Wq, Wk, Wv, W1, ca, cp, lens, Mxf, W1f, ord, out);
    hipLaunchKernelGGL(k_main, dim3(NN), dim3(512), 0, stream,
                       E, ht, evt, codes, lens, ca, cp, Mxf, ord, Rbf);
    hipLaunchKernelGGL(k_mlp,  dim3(NN / 16), dim3(256), 0, stream,
                       demo, labels, b1, W2, b2, Rbf, W1f, out);
}